// Round 1
// baseline (323.295 us; speedup 1.0000x reference)
//
#include <hip/hip_runtime.h>

// Problem constants (from reference): B=16, C=1, H=1024, W=1024, fp32.
#define HH 1024
#define WW 1024
#define BG_W 1.0f
#define DBG_W 5.0f
#define EDGE_W 20.0f

__device__ __forceinline__ float loss_elem(float x, float t, float dil) {
    // weight: target>0.5 -> 20, elif dilated>0.5 -> 5, else 1
    float w = (t > 0.5f) ? EDGE_W : ((dil > 0.5f) ? DBG_W : BG_W);
    // BCE with logits: max(x,0) - x*t + log1p(exp(-|x|))
    return w * (fmaxf(x, 0.0f) - x * t + log1pf(expf(-fabsf(x))));
}

__global__ __launch_bounds__(256) void dilatedweightBCE_kernel(
        const float* __restrict__ pred,
        const float* __restrict__ target,
        float* __restrict__ out,
        float inv_n) {
    // One block per (image b, row h). 256 threads * 4 cols = 1024 = WW.
    // svmax layout: [3] = left halo (col -1), [4 .. 4+WW-1] = vertical max,
    // [4+WW] = right halo (col WW). Offset +4 keeps b128 LDS ops 16B-aligned.
    __shared__ float svmax[4 + WW + 4];
    __shared__ float swave[4];

    const int h   = blockIdx.x;
    const int b   = blockIdx.y;
    const int tid = threadIdx.x;
    const size_t rowbase = ((size_t)b * HH + h) * WW;

    const float4* trow = (const float4*)(target + rowbase);
    float4 t0 = trow[tid];

    // vertical max over rows h-1, h, h+1 (outside rows contribute 0, which is
    // equivalent to the -inf SAME padding since target >= 0 and we only test >0.5)
    float4 vm = t0;
    if (h > 0) {
        float4 tm = ((const float4*)(target + rowbase - WW))[tid];
        vm.x = fmaxf(vm.x, tm.x); vm.y = fmaxf(vm.y, tm.y);
        vm.z = fmaxf(vm.z, tm.z); vm.w = fmaxf(vm.w, tm.w);
    }
    if (h < HH - 1) {
        float4 tp = ((const float4*)(target + rowbase + WW))[tid];
        vm.x = fmaxf(vm.x, tp.x); vm.y = fmaxf(vm.y, tp.y);
        vm.z = fmaxf(vm.z, tp.z); vm.w = fmaxf(vm.w, tp.w);
    }

    ((float4*)(svmax + 4))[tid] = vm;   // 16B-aligned ds_write_b128
    if (tid == 0) { svmax[3] = 0.0f; svmax[4 + WW] = 0.0f; }
    __syncthreads();

    const int c = tid * 4;
    float  l = svmax[3 + c];                       // ds_read_b32
    float4 m = *(const float4*)(svmax + 4 + c);    // ds_read_b128 (aligned)
    float  r = svmax[8 + c];                       // ds_read_b32

    float d0 = fmaxf(fmaxf(l,   m.x), m.y);
    float d1 = fmaxf(fmaxf(m.x, m.y), m.z);
    float d2 = fmaxf(fmaxf(m.y, m.z), m.w);
    float d3 = fmaxf(fmaxf(m.z, m.w), r);

    float4 x = ((const float4*)(pred + rowbase))[tid];

    float s = 0.0f;
    s += loss_elem(x.x, t0.x, d0);
    s += loss_elem(x.y, t0.y, d1);
    s += loss_elem(x.z, t0.z, d2);
    s += loss_elem(x.w, t0.w, d3);

    // wave (64-lane) shuffle reduction
    #pragma unroll
    for (int off = 32; off > 0; off >>= 1)
        s += __shfl_down(s, off);

    const int wave = tid >> 6;
    const int lane = tid & 63;
    if (lane == 0) swave[wave] = s;
    __syncthreads();
    if (tid == 0) {
        float tot = swave[0] + swave[1] + swave[2] + swave[3];
        atomicAdd(out, tot * inv_n);
    }
}

extern "C" void kernel_launch(void* const* d_in, const int* in_sizes, int n_in,
                              void* d_out, int out_size, void* d_ws, size_t ws_size,
                              hipStream_t stream) {
    const float* pred   = (const float*)d_in[0];
    const float* target = (const float*)d_in[1];
    float* out = (float*)d_out;

    const int n  = in_sizes[0];              // B*C*H*W
    const int Bn = n / (HH * WW);            // batch (16)

    // d_out is re-poisoned to 0xAA before every timed launch; zero it ourselves.
    hipMemsetAsync(d_out, 0, sizeof(float), stream);

    dim3 grid(HH, Bn);
    dilatedweightBCE_kernel<<<grid, 256, 0, stream>>>(pred, target, out,
                                                      1.0f / (float)n);
}

// Round 2
// 158.204 us; speedup vs baseline: 2.0435x; 2.0435x over previous
//
#include <hip/hip_runtime.h>

// Problem constants (from reference): B=16, C=1, H=1024, W=1024, fp32.
#define HH 1024
#define WW 1024
#define ROWS 8           // rows per block
#define NT 256           // threads per block; NT*4 == WW
#define W4 (WW / 4)      // row length in float4

__device__ __forceinline__ float4 fmax4(float4 a, float4 b) {
    return make_float4(fmaxf(a.x, b.x), fmaxf(a.y, b.y),
                       fmaxf(a.z, b.z), fmaxf(a.w, b.w));
}

__device__ __forceinline__ float loss_elem(float x, float t, float dil) {
    // weight: target>0.5 -> 20, elif dilated>0.5 -> 5, else 1
    float w = (t > 0.5f) ? 20.0f : ((dil > 0.5f) ? 5.0f : 1.0f);
    // BCE with logits: max(x,0) - x*t + log1p(exp(-|x|))
    // softplus(-|x|) via HW v_exp_f32 / v_log_f32: arg of log is in [1,2],
    // rel err ~1e-5 -- far below the 5.2e-2 harness threshold.
    float a  = fabsf(x);
    float sp = __logf(1.0f + __expf(-a));
    return w * (fmaxf(x, 0.0f) - x * t + sp);
}

__global__ __launch_bounds__(256) void dilatedweightBCE_kernel(
        const float* __restrict__ pred,
        const float* __restrict__ target,
        float* __restrict__ out,
        float inv_n) {
    // One block per (image b, 8-row band). Rolling registers give each target
    // row exactly one load per block; LDS double-buffer -> 1 sync per row.
    // sv layout per buffer: [3]=left halo(-1), [4..4+WW)=vmax, [4+WW]=right halo.
    // Offset +4 keeps ds_write_b128 / ds_read_b128 16B-aligned.
    __shared__ float sv[2][4 + WW + 4];
    __shared__ float swave[4];

    const int tid = threadIdx.x;
    const int b   = blockIdx.y;
    const int h0  = blockIdx.x * ROWS;

    const float4* tg = (const float4*)(target + (size_t)b * HH * WW);
    const float4* pg = (const float4*)(pred   + (size_t)b * HH * WW);

    if (tid == 0) {  // halos are 0 for every row (target >= 0, test is >0.5)
        sv[0][3] = 0.0f; sv[0][4 + WW] = 0.0f;
        sv[1][3] = 0.0f; sv[1][4 + WW] = 0.0f;
    }

    const float4 zero = make_float4(0.0f, 0.0f, 0.0f, 0.0f);
    float4 t_prev = (h0 > 0) ? tg[(size_t)(h0 - 1) * W4 + tid] : zero;
    float4 t_cur  = tg[(size_t)h0 * W4 + tid];

    float s = 0.0f;
    #pragma unroll
    for (int r = 0; r < ROWS; ++r) {
        const int h = h0 + r;
        float4 t_next = (h < HH - 1) ? tg[(size_t)(h + 1) * W4 + tid] : zero;
        float4 x      = pg[(size_t)h * W4 + tid];      // issue early, overlap

        float4 vm = fmax4(fmax4(t_prev, t_cur), t_next);

        float* buf = sv[r & 1];
        ((float4*)(buf + 4))[tid] = vm;                // ds_write_b128 aligned
        __syncthreads();

        const int c = tid * 4;
        float  l = buf[3 + c];
        float4 m = *(const float4*)(buf + 4 + c);      // ds_read_b128 aligned
        float  rr = buf[8 + c];

        float d0 = fmaxf(l,   fmaxf(m.x, m.y));
        float d1 = fmaxf(m.x, fmaxf(m.y, m.z));
        float d2 = fmaxf(m.y, fmaxf(m.z, m.w));
        float d3 = fmaxf(m.z, fmaxf(m.w, rr));

        s += loss_elem(x.x, t_cur.x, d0);
        s += loss_elem(x.y, t_cur.y, d1);
        s += loss_elem(x.z, t_cur.z, d2);
        s += loss_elem(x.w, t_cur.w, d3);

        t_prev = t_cur;
        t_cur  = t_next;
        // next iteration writes the OTHER buffer, so no second sync needed
    }

    // wave (64-lane) shuffle reduction, then cross-wave via LDS
    #pragma unroll
    for (int off = 32; off > 0; off >>= 1)
        s += __shfl_down(s, off);

    const int wave = tid >> 6;
    const int lane = tid & 63;
    if (lane == 0) swave[wave] = s;
    __syncthreads();
    if (tid == 0) {
        float tot = swave[0] + swave[1] + swave[2] + swave[3];
        atomicAdd(out, tot * inv_n);   // 2048 atomics total
    }
}

extern "C" void kernel_launch(void* const* d_in, const int* in_sizes, int n_in,
                              void* d_out, int out_size, void* d_ws, size_t ws_size,
                              hipStream_t stream) {
    const float* pred   = (const float*)d_in[0];
    const float* target = (const float*)d_in[1];
    float* out = (float*)d_out;

    const int n  = in_sizes[0];              // B*C*H*W
    const int Bn = n / (HH * WW);            // batch (16)

    // d_out is re-poisoned to 0xAA before every timed launch; zero it ourselves.
    hipMemsetAsync(d_out, 0, sizeof(float), stream);

    dim3 grid(HH / ROWS, Bn);
    dilatedweightBCE_kernel<<<grid, NT, 0, stream>>>(pred, target, out,
                                                     1.0f / (float)n);
}